// Round 3
// baseline (439.214 us; speedup 1.0000x reference)
//
#include <hip/hip_runtime.h>

// Problem constants (from reference)
constexpr int B = 256, L = 500, D = 3, C = 32, I = 35, H = 512, O = 15, M = 5, J = 35;
constexpr int JP = 48;   // out-cols padded to 3 MFMA n-tiles
constexpr int KP = 520;  // padded K leading dim for Vt / LDS (breaks pow2 banks)

typedef __attribute__((ext_vector_type(8))) short short8;  // 8 fp16 = MFMA A/B frag
typedef __attribute__((ext_vector_type(4))) float f32x4;   // MFMA C/D frag

// -------------------------------------------------------------------------
// k0x: xT[l][i][b] = concat(inputs,z)[b,l,i]  (fp32, coalesced writes by b)
// grid (I, L) x-fastest so all i of one l are adjacent -> z lines L2/L3-hit.
// -------------------------------------------------------------------------
__global__ __launch_bounds__(256) void k0x(const float* __restrict__ inp,
                                           const float* __restrict__ z,
                                           float* __restrict__ xT) {
  const int i = blockIdx.x, l = blockIdx.y, b = threadIdx.x;
  float v = (i < D) ? inp[(b * L + l) * D + i] : z[(b * L + l) * C + (i - D)];
  xT[((size_t)l * I + i) * B + b] = v;
}

// -------------------------------------------------------------------------
// k0v: Vt[l][j][k] fp16 [L][48][520] from V_mu/V_sigma/V_pi fp32 [l][k][j].
// Done ONCE so k3's per-block staging is a straight memcpy. Rows 35..47 zero.
// -------------------------------------------------------------------------
__global__ __launch_bounds__(256) void k0v(const float* __restrict__ Vmu,
                                           const float* __restrict__ Vsg,
                                           const float* __restrict__ Vpi,
                                           _Float16* __restrict__ Vt) {
  const int l = blockIdx.x, tid = threadIdx.x;
  _Float16* dst = Vt + (size_t)l * JP * KP;
  const float* vm = Vmu + (size_t)l * H * O;
  const float* vs = Vsg + (size_t)l * H * O;
  const float* vp = Vpi + (size_t)l * H * M;
  for (int idx = tid; idx < H * O; idx += 256) {
    int k = idx / O, j = idx - k * O;
    dst[j * KP + k]       = (_Float16)vm[idx];
    dst[(O + j) * KP + k] = (_Float16)vs[idx];
  }
  for (int idx = tid; idx < H * M; idx += 256) {
    int k = idx / M, j = idx - k * M;
    dst[(2 * O + j) * KP + k] = (_Float16)vp[idx];
  }
  for (int idx = tid; idx < (JP - J) * KP; idx += 256) {  // zero n-pad rows
    int j = idx / KP, k = idx - j * KP;
    dst[(J + j) * KP + k] = (_Float16)0.f;
  }
}

// -------------------------------------------------------------------------
// k1: c[l,b,h] = sum_i xT[l,i,b] * W[l,i,h], fp16 out [L][B][H].
// grid (H/64, L) x-fastest -> 8 h-chunk blocks of one l adjacent (X L3-hit).
// Staging fully coalesced, shift-only indexing. Thread: 4b x 16h fp32 acc.
// -------------------------------------------------------------------------
__global__ __launch_bounds__(256) void k1_c(const float* __restrict__ xT,
                                            const float* __restrict__ W,
                                            _Float16* __restrict__ cBH) {
  const int h0 = blockIdx.x * 64;
  const int l  = blockIdx.y;
  __shared__ __align__(16) float Xs[I][B];   // 35.8 KB
  __shared__ __align__(16) float Ws[I][64];  // 9.0 KB
  const int tid = threadIdx.x;

  const float* xsrc = xT + (size_t)l * I * B;
  for (int f = tid; f < (I * B) / 4; f += 256) {  // 2240 float4, coalesced
    int i = f >> 6, c = (f & 63) * 4;
    *(float4*)&Xs[i][c] = *(const float4*)&xsrc[i * B + c];
  }
  for (int idx = tid; idx < I * 64; idx += 256) {
    int i = idx >> 6, hl = idx & 63;
    Ws[i][hl] = W[((size_t)l * I + i) * H + h0 + hl];
  }
  __syncthreads();

  const int th = tid & 3;   // h group of 16 (lane-minor -> contiguous stores)
  const int tb = tid >> 2;  // b group of 4
  float acc[4][16] = {};
#pragma unroll
  for (int k = 0; k < I; ++k) {
    float4 xv = *(const float4*)&Xs[k][tb * 4];
    float x[4] = {xv.x, xv.y, xv.z, xv.w};
    const float* wr = &Ws[k][th * 16];
#pragma unroll
    for (int c = 0; c < 4; ++c) {
      float4 wv = *(const float4*)&wr[c * 4];
      float w[4] = {wv.x, wv.y, wv.z, wv.w};
#pragma unroll
      for (int br = 0; br < 4; ++br)
#pragma unroll
        for (int hh = 0; hh < 4; ++hh)
          acc[br][c * 4 + hh] = fmaf(x[br], w[hh], acc[br][c * 4 + hh]);
    }
  }
#pragma unroll
  for (int br = 0; br < 4; ++br) {
    const int b = tb * 4 + br;
    __align__(16) _Float16 tmp[16];
#pragma unroll
    for (int hh = 0; hh < 16; ++hh) tmp[hh] = (_Float16)acc[br][hh];
    _Float16* dst = &cBH[((size_t)l * B + b) * H + h0 + th * 16];
    *(uint4*)dst = ((uint4*)tmp)[0];
    *(uint4*)(dst + 8) = ((uint4*)tmp)[1];
  }
}

// -------------------------------------------------------------------------
// k2: in-place exclusive scan over l per (b,h): h[l]=relu(b_enc+sum_{j<l}c[j])
// fp32 running sum, fp16 storage. 20-deep unroll -> 20 loads in flight.
// -------------------------------------------------------------------------
__global__ __launch_bounds__(256) void k2_scan(_Float16* __restrict__ cBH,
                                               const float* __restrict__ benc) {
  const int t = blockIdx.x * 256 + threadIdx.x;  // flat over B*H, h-minor
  const float be = benc[t & (H - 1)];
  const size_t stride = (size_t)B * H;
  size_t idx = (size_t)t;
  float run = 0.f;
#pragma unroll 1
  for (int l = 0; l < L; l += 20) {
    _Float16 v[20];
#pragma unroll
    for (int j = 0; j < 20; ++j) v[j] = cBH[idx + j * stride];
#pragma unroll
    for (int j = 0; j < 20; ++j) {
      cBH[idx + j * stride] = (_Float16)fmaxf(run + be, 0.f);
      run += (float)v[j];
    }
    idx += 20 * stride;
  }
}

// -------------------------------------------------------------------------
// k3: out[b,l,:] = h[l,b,:] @ Vt[l] + bias via fp16 MFMA.
// grid (4, L): block = 64 b x one l, 4 waves x 1 m-tile. V staging = straight
// uint4 memcpy from Vt (L3-resident). Barrier-free K-loop, A streams global.
// -------------------------------------------------------------------------
__global__ __launch_bounds__(256) void k3_proj(const _Float16* __restrict__ hBH,
                                               const _Float16* __restrict__ Vt,
                                               const float* __restrict__ bmu,
                                               const float* __restrict__ bsg,
                                               const float* __restrict__ bpi,
                                               float* __restrict__ out) {
  const int b0 = blockIdx.x * 64;
  const int l  = blockIdx.y;
  const int tid = threadIdx.x;
  __shared__ __align__(16) _Float16 Vs[JP * KP];  // 49,920 B
  __shared__ float biasS[JP];

  const _Float16* src = Vt + (size_t)l * JP * KP;
  for (int f = tid; f < (JP * KP) / 8; f += 256)  // 3120 uint4 copies
    ((uint4*)Vs)[f] = ((const uint4*)src)[f];
  if (tid < JP) {
    float bv = 0.f;
    if (tid < O)          bv = bmu[l * O + tid];
    else if (tid < 2 * O) bv = bsg[l * O + tid - O];
    else if (tid < J)     bv = bpi[l * M + tid - 2 * O];
    biasS[tid] = bv;
  }
  __syncthreads();

  const int wave = tid >> 6, lane = tid & 63;
  const int row16 = lane & 15, quad = lane >> 4;
  const int m = b0 + wave * 16;  // this wave's 16 b-rows
  f32x4 acc[3];
#pragma unroll
  for (int nt = 0; nt < 3; ++nt) acc[nt] = (f32x4){0.f, 0.f, 0.f, 0.f};

  const _Float16* Ab = hBH + (size_t)l * B * H + (size_t)(m + row16) * H;
#pragma unroll 4
  for (int kt = 0; kt < 16; ++kt) {  // K = 512 in steps of 32
    const int k0 = kt * 32 + quad * 8;
    short8 a  = *(const short8*)&Ab[k0];
    short8 f0 = *(const short8*)&Vs[(0 * 16 + row16) * KP + k0];
    short8 f1 = *(const short8*)&Vs[(1 * 16 + row16) * KP + k0];
    short8 f2 = *(const short8*)&Vs[(2 * 16 + row16) * KP + k0];
    acc[0] = __builtin_amdgcn_mfma_f32_16x16x32_f16(a, f0, acc[0], 0, 0, 0);
    acc[1] = __builtin_amdgcn_mfma_f32_16x16x32_f16(a, f1, acc[1], 0, 0, 0);
    acc[2] = __builtin_amdgcn_mfma_f32_16x16x32_f16(a, f2, acc[2], 0, 0, 0);
  }

  // D layout: col(j)=lane&15, row(b)=quad*4+reg. Skip padded j>=35.
#pragma unroll
  for (int nt = 0; nt < 3; ++nt) {
    const int j = nt * 16 + row16;
    if (j < J) {
      const float bias = biasS[j];
#pragma unroll
      for (int r = 0; r < 4; ++r) {
        const int b = m + quad * 4 + r;
        out[((size_t)b * L + l) * J + j] = acc[nt][r] + bias;
      }
    }
  }
}

extern "C" void kernel_launch(void* const* d_in, const int* in_sizes, int n_in,
                              void* d_out, int out_size, void* d_ws, size_t ws_size,
                              hipStream_t stream) {
  const float* inp  = (const float*)d_in[0];
  const float* z    = (const float*)d_in[1];
  const float* Wenc = (const float*)d_in[2];
  const float* benc = (const float*)d_in[3];
  const float* Vmu  = (const float*)d_in[4];
  const float* bmu  = (const float*)d_in[5];
  const float* Vsg  = (const float*)d_in[6];
  const float* bsg  = (const float*)d_in[7];
  const float* Vpi  = (const float*)d_in[8];
  const float* bpi  = (const float*)d_in[9];
  float* out = (float*)d_out;

  // Workspace layout (fp16 intermediates): 131.1 + 17.9 + 25.0 = 174 MB
  char* ws = (char*)d_ws;
  _Float16* cBH = (_Float16*)ws;                        // [L][B][H]  131,072,000 B
  float*    xT  = (float*)(ws + 131072000);             // [L][I][B]   17,920,000 B
  _Float16* Vt  = (_Float16*)(ws + 131072000 + 17920000);  // [L][48][520] 24,960,000 B

  k0x<<<dim3(I, L), 256, 0, stream>>>(inp, z, xT);
  k0v<<<dim3(L), 256, 0, stream>>>(Vmu, Vsg, Vpi, Vt);
  k1_c<<<dim3(H / 64, L), 256, 0, stream>>>(xT, Wenc, cBH);
  k2_scan<<<dim3((B * H) / 256), 256, 0, stream>>>(cBH, benc);
  k3_proj<<<dim3(B / 64, L), 256, 0, stream>>>(cBH, Vt, bmu, bsg, bpi, out);
}

// Round 4
// 344.993 us; speedup vs baseline: 1.2731x; 1.2731x over previous
//
#include <hip/hip_runtime.h>

// Problem constants (from reference)
constexpr int B = 256, L = 500, D = 3, C = 32, I = 35, H = 512, O = 15, M = 5, J = 35;
constexpr int KP1 = 64;  // k1 K-dim (I=35) zero-padded to 2 MFMA k-steps
constexpr int JP = 48;   // out-cols padded to 3 MFMA n-tiles
constexpr int KPV = 520; // padded K leading dim for Vt / k3 LDS

typedef __attribute__((ext_vector_type(8))) short short8;  // 8 fp16 = MFMA A/B frag
typedef __attribute__((ext_vector_type(4))) float f32x4;   // MFMA C/D frag

// -------------------------------------------------------------------------
// k0x: xTf16[l][b][k] (K padded to 64, zeros for k>=35) from inputs/z fp32.
// Gather through LDS (row pad 66 -> 2-way bank max), coalesced uint writes.
// -------------------------------------------------------------------------
__global__ __launch_bounds__(256) void k0x(const float* __restrict__ inp,
                                           const float* __restrict__ z,
                                           _Float16* __restrict__ xT) {
  const int l = blockIdx.x, tid = threadIdx.x;
  __shared__ _Float16 xs[B][66];
  const float* ip = inp + ((size_t)tid * L + l) * D;
  const float* zp = z + ((size_t)tid * L + l) * C;
#pragma unroll
  for (int i = 0; i < D; ++i) xs[tid][i] = (_Float16)ip[i];
#pragma unroll 8
  for (int i = 0; i < C; ++i) xs[tid][D + i] = (_Float16)zp[i];
  __syncthreads();
  unsigned int* dst = (unsigned int*)(xT + (size_t)l * B * KP1);
  for (int f = tid; f < B * KP1 / 2; f += 256) {
    int b = f >> 5, k = (f & 31) * 2;
    unsigned int lo = (k < I)     ? *(const unsigned short*)&xs[b][k]     : 0u;
    unsigned int hi = (k + 1 < I) ? *(const unsigned short*)&xs[b][k + 1] : 0u;
    dst[f] = lo | (hi << 16);
  }
}

// -------------------------------------------------------------------------
// k0w: Wt[l][h][k] fp16 (K padded 64) from W_enc fp32 [l][i][h] (transpose).
// LDS tile [512][37] (odd pad -> ~2-way max), coalesced reads and writes.
// -------------------------------------------------------------------------
__global__ __launch_bounds__(256) void k0w(const float* __restrict__ W,
                                           _Float16* __restrict__ Wt) {
  const int l = blockIdx.x, tid = threadIdx.x;
  __shared__ _Float16 ws[H][37];
  for (int f = tid; f < I * H; f += 256) {
    int i = f >> 9, h = f & 511;
    ws[h][i] = (_Float16)W[((size_t)l * I + i) * H + h];
  }
  __syncthreads();
  unsigned int* dst = (unsigned int*)(Wt + (size_t)l * H * KP1);
  for (int f = tid; f < H * KP1 / 2; f += 256) {
    int h = f >> 5, k = (f & 31) * 2;
    unsigned int lo = (k < I)     ? *(const unsigned short*)&ws[h][k]     : 0u;
    unsigned int hi = (k + 1 < I) ? *(const unsigned short*)&ws[h][k + 1] : 0u;
    dst[f] = lo | (hi << 16);
  }
}

// -------------------------------------------------------------------------
// k0v: Vt[l][j][k] fp16 [L][48][520] from V_mu/V_sigma/V_pi fp32 [l][k][j].
// -------------------------------------------------------------------------
__global__ __launch_bounds__(256) void k0v(const float* __restrict__ Vmu,
                                           const float* __restrict__ Vsg,
                                           const float* __restrict__ Vpi,
                                           _Float16* __restrict__ Vt) {
  const int l = blockIdx.x, tid = threadIdx.x;
  _Float16* dst = Vt + (size_t)l * JP * KPV;
  const float* vm = Vmu + (size_t)l * H * O;
  const float* vs = Vsg + (size_t)l * H * O;
  const float* vp = Vpi + (size_t)l * H * M;
  for (int idx = tid; idx < H * O; idx += 256) {
    int k = idx / O, j = idx - k * O;
    dst[j * KPV + k]       = (_Float16)vm[idx];
    dst[(O + j) * KPV + k] = (_Float16)vs[idx];
  }
  for (int idx = tid; idx < H * M; idx += 256) {
    int k = idx / M, j = idx - k * M;
    dst[(2 * O + j) * KPV + k] = (_Float16)vp[idx];
  }
  for (int idx = tid; idx < (JP - J) * KPV; idx += 256) {
    int j = idx / KPV, k = idx - j * KPV;
    dst[(J + j) * KPV + k] = (_Float16)0.f;
  }
}

// -------------------------------------------------------------------------
// k1: c[l,b,h] = x[l,b,:] @ W[l,:,h] via fp16 MFMA, NO LDS, NO barriers.
// Block = 64 b x 128 h x one l; wave = 16 b (m-tile) x 128 h (8 n-tiles).
// A/B frags load straight from global (block slab 24 KB -> L1-resident).
// VGPR ~90 -> 4 waves/SIMD.
// -------------------------------------------------------------------------
__global__ __launch_bounds__(256, 4) void k1_c(const _Float16* __restrict__ xT,
                                               const _Float16* __restrict__ Wt,
                                               _Float16* __restrict__ cBH) {
  const int b0 = blockIdx.x * 64, h0 = blockIdx.y * 128, l = blockIdx.z;
  const int wave = threadIdx.x >> 6, lane = threadIdx.x & 63;
  const int row16 = lane & 15, quad = lane >> 4;
  const int m = b0 + wave * 16;

  const _Float16* Ap = xT + ((size_t)l * B + m + row16) * KP1 + quad * 8;
  const _Float16* Bp = Wt + ((size_t)l * H + h0 + row16) * KP1 + quad * 8;

  f32x4 acc[8];
#pragma unroll
  for (int nt = 0; nt < 8; ++nt) acc[nt] = (f32x4){0.f, 0.f, 0.f, 0.f};

#pragma unroll
  for (int kt = 0; kt < 2; ++kt) {
    short8 a = *(const short8*)(Ap + kt * 32);
    short8 bb[8];
#pragma unroll
    for (int nt = 0; nt < 8; ++nt)
      bb[nt] = *(const short8*)(Bp + (size_t)nt * 16 * KP1 + kt * 32);
#pragma unroll
    for (int nt = 0; nt < 8; ++nt)
      acc[nt] = __builtin_amdgcn_mfma_f32_16x16x32_f16(a, bb[nt], acc[nt], 0, 0, 0);
  }

  // D layout: col(h)=lane&15, row(b)=quad*4+r
  _Float16* cb = cBH + (size_t)l * B * H;
#pragma unroll
  for (int nt = 0; nt < 8; ++nt) {
    const int h = h0 + nt * 16 + row16;
#pragma unroll
    for (int r = 0; r < 4; ++r) {
      const int b = m + quad * 4 + r;
      cb[(size_t)b * H + h] = (_Float16)acc[nt][r];
    }
  }
}

// -------------------------------------------------------------------------
// k2: in-place exclusive scan over l per (b,h): h[l]=relu(b_enc+sum_{j<l}c[j])
// fp32 running sum, fp16 storage. 20-deep unroll -> 20 loads in flight.
// -------------------------------------------------------------------------
__global__ __launch_bounds__(256, 4) void k2_scan(_Float16* __restrict__ cBH,
                                                  const float* __restrict__ benc) {
  const int t = blockIdx.x * 256 + threadIdx.x;  // flat over B*H, h-minor
  const float be = benc[t & (H - 1)];
  const size_t stride = (size_t)B * H;
  size_t idx = (size_t)t;
  float run = 0.f;
#pragma unroll 1
  for (int l = 0; l < L; l += 20) {
    _Float16 v[20];
#pragma unroll
    for (int j = 0; j < 20; ++j) v[j] = cBH[idx + j * stride];
#pragma unroll
    for (int j = 0; j < 20; ++j) {
      cBH[idx + j * stride] = (_Float16)fmaxf(run + be, 0.f);
      run += (float)v[j];
    }
    idx += 20 * stride;
  }
}

// -------------------------------------------------------------------------
// k3: out[b,l,:] = h[l,b,:] @ Vt[l] + bias via fp16 MFMA.
// grid (4, L): block = 64 b x one l. V staging = straight uint4 memcpy.
// -------------------------------------------------------------------------
__global__ __launch_bounds__(256) void k3_proj(const _Float16* __restrict__ hBH,
                                               const _Float16* __restrict__ Vt,
                                               const float* __restrict__ bmu,
                                               const float* __restrict__ bsg,
                                               const float* __restrict__ bpi,
                                               float* __restrict__ out) {
  const int b0 = blockIdx.x * 64;
  const int l  = blockIdx.y;
  const int tid = threadIdx.x;
  __shared__ __align__(16) _Float16 Vs[JP * KPV];  // 49,920 B
  __shared__ float biasS[JP];

  const _Float16* src = Vt + (size_t)l * JP * KPV;
  for (int f = tid; f < (JP * KPV) / 8; f += 256)
    ((uint4*)Vs)[f] = ((const uint4*)src)[f];
  if (tid < JP) {
    float bv = 0.f;
    if (tid < O)          bv = bmu[l * O + tid];
    else if (tid < 2 * O) bv = bsg[l * O + tid - O];
    else if (tid < J)     bv = bpi[l * M + tid - 2 * O];
    biasS[tid] = bv;
  }
  __syncthreads();

  const int wave = tid >> 6, lane = tid & 63;
  const int row16 = lane & 15, quad = lane >> 4;
  const int m = b0 + wave * 16;
  f32x4 acc[3];
#pragma unroll
  for (int nt = 0; nt < 3; ++nt) acc[nt] = (f32x4){0.f, 0.f, 0.f, 0.f};

  const _Float16* Ab = hBH + (size_t)l * B * H + (size_t)(m + row16) * H;
#pragma unroll 4
  for (int kt = 0; kt < 16; ++kt) {
    const int k0 = kt * 32 + quad * 8;
    short8 a  = *(const short8*)&Ab[k0];
    short8 f0 = *(const short8*)&Vs[(0 * 16 + row16) * KPV + k0];
    short8 f1 = *(const short8*)&Vs[(1 * 16 + row16) * KPV + k0];
    short8 f2 = *(const short8*)&Vs[(2 * 16 + row16) * KPV + k0];
    acc[0] = __builtin_amdgcn_mfma_f32_16x16x32_f16(a, f0, acc[0], 0, 0, 0);
    acc[1] = __builtin_amdgcn_mfma_f32_16x16x32_f16(a, f1, acc[1], 0, 0, 0);
    acc[2] = __builtin_amdgcn_mfma_f32_16x16x32_f16(a, f2, acc[2], 0, 0, 0);
  }

  // D layout: col(j)=lane&15, row(b)=quad*4+r. Skip padded j>=35.
#pragma unroll
  for (int nt = 0; nt < 3; ++nt) {
    const int j = nt * 16 + row16;
    if (j < J) {
      const float bias = biasS[j];
#pragma unroll
      for (int r = 0; r < 4; ++r) {
        const int b = m + quad * 4 + r;
        out[((size_t)b * L + l) * J + j] = acc[nt][r] + bias;
      }
    }
  }
}

extern "C" void kernel_launch(void* const* d_in, const int* in_sizes, int n_in,
                              void* d_out, int out_size, void* d_ws, size_t ws_size,
                              hipStream_t stream) {
  const float* inp  = (const float*)d_in[0];
  const float* z    = (const float*)d_in[1];
  const float* Wenc = (const float*)d_in[2];
  const float* benc = (const float*)d_in[3];
  const float* Vmu  = (const float*)d_in[4];
  const float* bmu  = (const float*)d_in[5];
  const float* Vsg  = (const float*)d_in[6];
  const float* bsg  = (const float*)d_in[7];
  const float* Vpi  = (const float*)d_in[8];
  const float* bpi  = (const float*)d_in[9];
  float* out = (float*)d_out;

  // Workspace (all fp16): cBH 131.07 + xT 16.38 + Wt 32.77 + Vt 24.96 = 205.2 MB
  char* ws = (char*)d_ws;
  _Float16* cBH = (_Float16*)ws;                          // [L][B][H]
  _Float16* xT  = (_Float16*)(ws + 131072000);            // [L][B][64]
  _Float16* Wt  = (_Float16*)(ws + 131072000 + 16384000); // [L][H][64]
  _Float16* Vt  = (_Float16*)(ws + 131072000 + 16384000 + 32768000);  // [L][48][520]

  k0x<<<dim3(L), 256, 0, stream>>>(inp, z, xT);
  k0w<<<dim3(L), 256, 0, stream>>>(Wenc, Wt);
  k0v<<<dim3(L), 256, 0, stream>>>(Vmu, Vsg, Vpi, Vt);
  k1_c<<<dim3(B / 64, H / 128, L), 256, 0, stream>>>(xT, Wt, cBH);
  k2_scan<<<dim3((B * H) / 256), 256, 0, stream>>>(cBH, benc);
  k3_proj<<<dim3(B / 64, L), 256, 0, stream>>>(cBH, Vt, bmu, bsg, bpi, out);
}

// Round 5
// 323.032 us; speedup vs baseline: 1.3597x; 1.0680x over previous
//
#include <hip/hip_runtime.h>

// Problem constants (from reference)
constexpr int B = 256, L = 500, D = 3, C = 32, I = 35, H = 512, O = 15, M = 5, J = 35;
constexpr int KP1 = 64;  // k1 K-dim (I=35) zero-padded to 4 MFMA k-steps (32x32x16)
constexpr int JP = 48;   // out-cols padded to 3 MFMA n-tiles
constexpr int KPV = 520; // padded K leading dim for Vt

typedef __attribute__((ext_vector_type(8))) _Float16 half8;  // MFMA A/B frag
typedef __attribute__((ext_vector_type(4))) float f32x4;     // 16x16 C/D frag
typedef __attribute__((ext_vector_type(16))) float f32x16;   // 32x32 C/D frag

// -------------------------------------------------------------------------
// k0x: xT[l][b][k] fp16, K padded to 64 (zeros k>=35). float4 z loads (each
// lane's 128B row is contiguous; L1 merges the 4 stride-64KB passes).
// LDS row 38 (19 words, odd) -> conflict-free staging.
// -------------------------------------------------------------------------
__global__ __launch_bounds__(256) void k0x(const float* __restrict__ inp,
                                           const float* __restrict__ z,
                                           _Float16* __restrict__ xT) {
  const int l = blockIdx.x, tid = threadIdx.x;  // tid = b
  __shared__ _Float16 xs[B][38];
  const float* ip = inp + ((size_t)tid * L + l) * D;
  const float4* zp = (const float4*)(z + ((size_t)tid * L + l) * C);
  xs[tid][0] = (_Float16)ip[0];
  xs[tid][1] = (_Float16)ip[1];
  xs[tid][2] = (_Float16)ip[2];
#pragma unroll
  for (int q = 0; q < 8; ++q) {
    float4 v = zp[q];
    xs[tid][D + q * 4 + 0] = (_Float16)v.x;
    xs[tid][D + q * 4 + 1] = (_Float16)v.y;
    xs[tid][D + q * 4 + 2] = (_Float16)v.z;
    xs[tid][D + q * 4 + 3] = (_Float16)v.w;
  }
  __syncthreads();
  unsigned int* dst = (unsigned int*)(xT + (size_t)l * B * KP1);
  for (int f = tid; f < B * KP1 / 2; f += 256) {
    int b = f >> 5, k = (f & 31) * 2;
    unsigned int lo = (k < I)     ? *(const unsigned short*)&xs[b][k]     : 0u;
    unsigned int hi = (k + 1 < I) ? *(const unsigned short*)&xs[b][k + 1] : 0u;
    dst[f] = lo | (hi << 16);
  }
}

// -------------------------------------------------------------------------
// k0w: Wt[l][h][k] fp16 (K padded 64) from W_enc fp32 [l][i][h] (transpose).
// -------------------------------------------------------------------------
__global__ __launch_bounds__(256) void k0w(const float* __restrict__ W,
                                           _Float16* __restrict__ Wt) {
  const int l = blockIdx.x, tid = threadIdx.x;
  __shared__ _Float16 ws[H][37];
  for (int f = tid; f < I * H; f += 256) {
    int i = f >> 9, h = f & 511;
    ws[h][i] = (_Float16)W[((size_t)l * I + i) * H + h];
  }
  __syncthreads();
  unsigned int* dst = (unsigned int*)(Wt + (size_t)l * H * KP1);
  for (int f = tid; f < H * KP1 / 2; f += 256) {
    int h = f >> 5, k = (f & 31) * 2;
    unsigned int lo = (k < I)     ? *(const unsigned short*)&ws[h][k]     : 0u;
    unsigned int hi = (k + 1 < I) ? *(const unsigned short*)&ws[h][k + 1] : 0u;
    dst[f] = lo | (hi << 16);
  }
}

// -------------------------------------------------------------------------
// k0v: Vt[l][j][k] fp16 [L][48][520]. Scatter-transpose into LDS, then
// LINEAR uint4 global writes (round-4 version did scattered 2B stores).
// -------------------------------------------------------------------------
__global__ __launch_bounds__(256) void k0v(const float* __restrict__ Vmu,
                                           const float* __restrict__ Vsg,
                                           const float* __restrict__ Vpi,
                                           _Float16* __restrict__ Vt) {
  const int l = blockIdx.x, tid = threadIdx.x;
  __shared__ __align__(16) _Float16 Vs[JP * KPV];  // 49,920 B
  for (int f = tid; f < (JP * KPV) / 8; f += 256) ((uint4*)Vs)[f] = (uint4){0, 0, 0, 0};
  __syncthreads();
  const float* vm = Vmu + (size_t)l * H * O;
  const float* vs = Vsg + (size_t)l * H * O;
  const float* vp = Vpi + (size_t)l * H * M;
  for (int idx = tid; idx < H * O; idx += 256) {
    int k = idx / O, j = idx - k * O;
    Vs[j * KPV + k]       = (_Float16)vm[idx];
    Vs[(O + j) * KPV + k] = (_Float16)vs[idx];
  }
  for (int idx = tid; idx < H * M; idx += 256) {
    int k = idx / M, j = idx - k * M;
    Vs[(2 * O + j) * KPV + k] = (_Float16)vp[idx];
  }
  __syncthreads();
  uint4* dst = (uint4*)(Vt + (size_t)l * JP * KPV);
  for (int f = tid; f < (JP * KPV) / 8; f += 256) dst[f] = ((const uint4*)Vs)[f];
}

// -------------------------------------------------------------------------
// k1: c[l,b,h] via 32x32x16 fp16 MFMA, no LDS, no barriers.
// Block = 128 b x 128 h x one l; wave = 32 b (m-tile) x 128 h (4 n-tiles).
// D layout: col(h)=lane&31 -> stores hit 64B-contiguous segments (full HBM
// lines), vs 32B with the 16x16 shape. 4000 blocks, 2x K-depth of round 4.
// -------------------------------------------------------------------------
__global__ __launch_bounds__(256, 4) void k1_c(const _Float16* __restrict__ xT,
                                               const _Float16* __restrict__ Wt,
                                               _Float16* __restrict__ cBH) {
  const int b0 = blockIdx.x * 128, h0 = blockIdx.y * 128, l = blockIdx.z;
  const int wave = threadIdx.x >> 6, lane = threadIdx.x & 63;
  const int ln31 = lane & 31, hi32 = lane >> 5;

  const _Float16* Ap = xT + ((size_t)l * B + b0 + wave * 32 + ln31) * KP1 + hi32 * 8;
  const _Float16* Bp = Wt + ((size_t)l * H + h0 + ln31) * KP1 + hi32 * 8;

  f32x16 acc[4];
#pragma unroll
  for (int nt = 0; nt < 4; ++nt)
#pragma unroll
    for (int r = 0; r < 16; ++r) acc[nt][r] = 0.f;

#pragma unroll
  for (int kt = 0; kt < 4; ++kt) {  // K = 64 in steps of 16
    half8 a = *(const half8*)(Ap + kt * 16);
#pragma unroll
    for (int nt = 0; nt < 4; ++nt) {
      half8 bb = *(const half8*)(Bp + (size_t)nt * 32 * KP1 + kt * 16);
      acc[nt] = __builtin_amdgcn_mfma_f32_32x32x16_f16(a, bb, acc[nt], 0, 0, 0);
    }
  }

  // D: col(h)=lane&31, row(b)=(reg&3)+8*(reg>>2)+4*(lane>>5)
  _Float16* cb = cBH + (size_t)l * B * H;
  const int bbase = b0 + wave * 32 + 4 * hi32;
  const int hcol  = h0 + ln31;
#pragma unroll
  for (int nt = 0; nt < 4; ++nt) {
    const int h = hcol + nt * 32;
#pragma unroll
    for (int reg = 0; reg < 16; ++reg) {
      const int b = bbase + (reg & 3) + 8 * (reg >> 2);
      cb[(size_t)b * H + h] = (_Float16)acc[nt][reg];
    }
  }
}

// -------------------------------------------------------------------------
// k2: in-place exclusive scan over l per (b,h). 2 fp16/thread (uint), 25-deep
// unroll: 65536 threads x 100 B = 6.5 MB in flight (> Little's-law ~5.7 MB).
// -------------------------------------------------------------------------
__global__ __launch_bounds__(256) void k2_scan(_Float16* __restrict__ cBH,
                                               const float* __restrict__ benc) {
  const int t = blockIdx.x * 256 + threadIdx.x;  // t < B*H/2
  const int h = (t * 2) & (H - 1);
  const float be0 = benc[h], be1 = benc[h + 1];
  unsigned int* p = (unsigned int*)cBH;
  const size_t stride = (size_t)B * H / 2;  // uints per l-plane
  size_t idx = (size_t)t;
  float run0 = 0.f, run1 = 0.f;
#pragma unroll 1
  for (int l = 0; l < L; l += 25) {
    unsigned int v[25];
#pragma unroll
    for (int j = 0; j < 25; ++j) v[j] = p[idx + j * stride];
#pragma unroll
    for (int j = 0; j < 25; ++j) {
      union { unsigned int u; _Float16 f[2]; } ov, cv;
      ov.f[0] = (_Float16)fmaxf(run0 + be0, 0.f);
      ov.f[1] = (_Float16)fmaxf(run1 + be1, 0.f);
      p[idx + j * stride] = ov.u;
      cv.u = v[j];
      run0 += (float)cv.f[0];
      run1 += (float)cv.f[1];
    }
    idx += 25 * stride;
  }
}

// -------------------------------------------------------------------------
// k3: out[b,l,:] = h[l,b,:] @ Vt[l] + bias via 16x16x32 fp16 MFMA.
// NO LDS, NO barrier: B-frags stream from Vt (L2/L3-resident, 64B segments
// per row); A-frags stream from hBH. grid (4, L), 8 waves/SIMD-capable.
// -------------------------------------------------------------------------
__global__ __launch_bounds__(256) void k3_proj(const _Float16* __restrict__ hBH,
                                               const _Float16* __restrict__ Vt,
                                               const float* __restrict__ bmu,
                                               const float* __restrict__ bsg,
                                               const float* __restrict__ bpi,
                                               float* __restrict__ out) {
  const int b0 = blockIdx.x * 64;
  const int l  = blockIdx.y;
  const int wave = threadIdx.x >> 6, lane = threadIdx.x & 63;
  const int row16 = lane & 15, quad = lane >> 4;
  const int m = b0 + wave * 16;

  f32x4 acc[3];
#pragma unroll
  for (int nt = 0; nt < 3; ++nt) acc[nt] = (f32x4){0.f, 0.f, 0.f, 0.f};

  const _Float16* Ab = hBH + ((size_t)l * B + m + row16) * H + quad * 8;
  const _Float16* Vb = Vt + (size_t)l * JP * KPV + (size_t)row16 * KPV + quad * 8;
#pragma unroll 4
  for (int kt = 0; kt < 16; ++kt) {  // K = 512 in steps of 32
    const int k0 = kt * 32;
    half8 a  = *(const half8*)(Ab + k0);
    half8 f0 = *(const half8*)(Vb + k0);
    half8 f1 = *(const half8*)(Vb + 16 * KPV + k0);
    half8 f2 = *(const half8*)(Vb + 32 * KPV + k0);
    acc[0] = __builtin_amdgcn_mfma_f32_16x16x32_f16(a, f0, acc[0], 0, 0, 0);
    acc[1] = __builtin_amdgcn_mfma_f32_16x16x32_f16(a, f1, acc[1], 0, 0, 0);
    acc[2] = __builtin_amdgcn_mfma_f32_16x16x32_f16(a, f2, acc[2], 0, 0, 0);
  }

  // D: col(j)=lane&15, row(b)=quad*4+r. Skip padded j>=35.
#pragma unroll
  for (int nt = 0; nt < 3; ++nt) {
    const int j = nt * 16 + row16;
    if (j < J) {
      const float bias = (j < O) ? bmu[l * O + j]
                       : (j < 2 * O) ? bsg[l * O + (j - O)]
                       : bpi[l * M + (j - 2 * O)];
#pragma unroll
      for (int r = 0; r < 4; ++r) {
        const int b = m + quad * 4 + r;
        out[((size_t)b * L + l) * J + j] = acc[nt][r] + bias;
      }
    }
  }
}

extern "C" void kernel_launch(void* const* d_in, const int* in_sizes, int n_in,
                              void* d_out, int out_size, void* d_ws, size_t ws_size,
                              hipStream_t stream) {
  const float* inp  = (const float*)d_in[0];
  const float* z    = (const float*)d_in[1];
  const float* Wenc = (const float*)d_in[2];
  const float* benc = (const float*)d_in[3];
  const float* Vmu  = (const float*)d_in[4];
  const float* bmu  = (const float*)d_in[5];
  const float* Vsg  = (const float*)d_in[6];
  const float* bsg  = (const float*)d_in[7];
  const float* Vpi  = (const float*)d_in[8];
  const float* bpi  = (const float*)d_in[9];
  float* out = (float*)d_out;

  // Workspace (all fp16): cBH 131.07 + xT 16.38 + Wt 32.77 + Vt 24.96 = 205.2 MB
  char* ws = (char*)d_ws;
  _Float16* cBH = (_Float16*)ws;                          // [L][B][H]
  _Float16* xT  = (_Float16*)(ws + 131072000);            // [L][B][64]
  _Float16* Wt  = (_Float16*)(ws + 131072000 + 16384000); // [L][H][64]
  _Float16* Vt  = (_Float16*)(ws + 131072000 + 16384000 + 32768000);  // [L][48][520]

  k0x<<<dim3(L), 256, 0, stream>>>(inp, z, xT);
  k0w<<<dim3(L), 256, 0, stream>>>(Wenc, Wt);
  k0v<<<dim3(L), 256, 0, stream>>>(Vmu, Vsg, Vpi, Vt);
  k1_c<<<dim3(B / 128, H / 128, L), 256, 0, stream>>>(xT, Wt, cBH);
  k2_scan<<<dim3((B * H / 2) / 256), 256, 0, stream>>>(cBH, benc);
  k3_proj<<<dim3(B / 64, L), 256, 0, stream>>>(cBH, Vt, bmu, bsg, bpi, out);
}